// Round 22
// baseline (187.386 us; speedup 1.0000x reference)
//
#include <hip/hip_runtime.h>
#include <hip/hip_bf16.h>

#define LRELU_SLOPE 0.2f
#define NBUK 256          // dst buckets (512 nodes each)
#define BCAP 9728         // per-bucket capacity (mean 8704, +11 sigma)
#define CH2 6144          // edges per partition block (6/thread, 1024 threads)

typedef unsigned int uint;
typedef unsigned short ushort;
typedef short bt8 __attribute__((ext_vector_type(8)));   // 8 bf16 (4 VGPRs)
typedef float fx4 __attribute__((ext_vector_type(4)));   // MFMA accumulator

__device__ __forceinline__ ushort f2bf(float f) {   // RNE
    uint u = __float_as_uint(f);
    return (ushort)((u + 0x7FFF + ((u >> 16) & 1)) >> 16);
}
__device__ __forceinline__ float bf2f(ushort h) {
    return __uint_as_float(((uint)h) << 16);
}

#define ACC8(e, hv) \
    acc[0] += (e) * bf2f((ushort)((hv).x & 0xffff)); \
    acc[1] += (e) * bf2f((ushort)((hv).x >> 16));    \
    acc[2] += (e) * bf2f((ushort)((hv).y & 0xffff)); \
    acc[3] += (e) * bf2f((ushort)((hv).y >> 16));    \
    acc[4] += (e) * bf2f((ushort)((hv).z & 0xffff)); \
    acc[5] += (e) * bf2f((ushort)((hv).z >> 16));    \
    acc[6] += (e) * bf2f((ushort)((hv).w & 0xffff)); \
    acc[7] += (e) * bf2f((ushort)((hv).w >> 16));

// per-edge step, 8-head gather: score computed in-register from hv (head ol)
#define EDGE_H8(sjv, LIVE) { \
    uint4 hv = *(const uint4*)(HB + (size_t)(sjv) * 64 + ol * 8); \
    float h0 = bf2f((ushort)(hv.x & 0xffff)), h1 = bf2f((ushort)(hv.x >> 16)); \
    float h2 = bf2f((ushort)(hv.y & 0xffff)), h3 = bf2f((ushort)(hv.y >> 16)); \
    float h4 = bf2f((ushort)(hv.z & 0xffff)), h5 = bf2f((ushort)(hv.z >> 16)); \
    float h6 = bf2f((ushort)(hv.w & 0xffff)), h7 = bf2f((ushort)(hv.w >> 16)); \
    float dt = h0*w0.x + h1*w0.y + h2*w0.z + h3*w0.w \
             + h4*w1.x + h5*w1.y + h6*w1.z + h7*w1.w; \
    float a_ = dt + adh; a_ = a_ > 0.f ? a_ : LRELU_SLOPE * a_; \
    float e = __expf(a_); \
    if (!(LIVE)) e = 0.f; \
    dsum += e; \
    acc[0] += e*h0; acc[1] += e*h1; acc[2] += e*h2; acc[3] += e*h3; \
    acc[4] += e*h4; acc[5] += e*h5; acc[6] += e*h6; acc[7] += e*h7; }

// ---- prep: W -> W^T bf16 (both layers) + init pcur ----
__global__ __launch_bounds__(256) void prep_init(
    const float* __restrict__ W1, const float* __restrict__ W2,
    ushort* __restrict__ WT1, ushort* __restrict__ WT2, int* __restrict__ pcur)
{
    int t = threadIdx.x;
    int idx = blockIdx.x * 256 + t;
    if (blockIdx.x == 0) pcur[t] = t * BCAP;
    if (idx < 64 * 256) {
        int c = idx >> 8, k = idx & 255;
        WT1[idx] = f2bf(W1[k * 64 + c]);
    }
    int i2 = idx - 64 * 256;
    if (i2 >= 0 && i2 < 64 * 64) {
        int c = i2 >> 6, k = i2 & 63;
        WT2[i2] = f2bf(W2[k * 64 + c]);
    }
}

// ---- phase 1: register-held partition (r9 standalone, 1024 threads) ----
__global__ __launch_bounds__(1024) void partition_pairs(
    const int* __restrict__ ei, int E_, int ET,
    int* __restrict__ pcur, uint* __restrict__ pairs)
{
    __shared__ int lcnt[NBUK], lsc[NBUK], lplace[NBUK], gpos[NBUK];
    const int t = threadIdx.x;
    const int base = blockIdx.x * CH2;
    const int total = min(CH2, ET - base);
    if (total <= 0) return;

    if (t < NBUK) lcnt[t] = 0;
    __syncthreads();

    uint pp[6]; int pk[6];
    #pragma unroll
    for (int i = 0; i < 6; ++i) {
        int idx = t + i * 1024;
        pk[i] = -1;
        if (idx < total) {
            int e = base + idx;
            int s, d;
            if (e < E_) { s = ei[e]; d = ei[E_ + e]; } else { s = d = e - E_; }
            pk[i] = d >> 9;
            pp[i] = (uint)s | ((uint)(d & 511) << 17);
            atomicAdd(&lcnt[pk[i]], 1);
        }
    }
    __syncthreads();

    if (t < NBUK) lsc[t] = lcnt[t];
    __syncthreads();
    for (int off = 1; off < NBUK; off <<= 1) {
        int add = 0;
        if (t < NBUK && t >= off) add = lsc[t - off];
        __syncthreads();
        if (t < NBUK) lsc[t] += add;
        __syncthreads();
    }
    if (t < NBUK) {
        int excl = lsc[t] - lcnt[t];
        lplace[t] = excl;
        int c = lcnt[t];
        gpos[t] = c ? (atomicAdd(&pcur[t], c) - excl) : 0;
    }
    __syncthreads();

    #pragma unroll
    for (int i = 0; i < 6; ++i) {
        if (pk[i] >= 0) {
            int slot = atomicAdd(&lplace[pk[i]], 1);
            pairs[gpos[pk[i]] + slot] = pp[i];
        }
    }
}

// ---- layer-1 GEMM: 256 thr, LDS W^T, FULL-ROW register prefetch, no K-loop barriers ----
__global__ __launch_bounds__(256) void gemm1_att(
    const float* __restrict__ X, const ushort* __restrict__ WT,
    ushort* __restrict__ OUT, float* __restrict__ a_dst,
    const float* __restrict__ att_d, int nrows)
{
    constexpr int K = 256, LDW = K + 8, NIT = K / 32;
    __shared__ ushort wt_l[64 * LDW];     // 33.8 KB -> 4 blocks/CU
    const int t = threadIdx.x;
    const int base = blockIdx.x * 64;

    for (int idx = t * 8; idx < 64 * K; idx += 256 * 8) {
        int r = idx / K, c = idx % K;
        *(uint4*)&wt_l[r * LDW + c] = *(const uint4*)&WT[idx];
    }
    __syncthreads();

    const int w = t >> 6, l = t & 63;
    const int frow = l & 15;
    const int kof = (l >> 4) * 8;
    const int arow = base + 16 * w + frow;
    const bool rowok = arow < nrows;
    const float4* xrow = (const float4*)(X + (size_t)arow * K + kof);
    fx4 acc[4] = {};

    // issue all 16 row loads up front (statically indexed -> registers, 16-deep MLP)
    float4 rx[16];
    const float4 z4 = make_float4(0.f, 0.f, 0.f, 0.f);
    #pragma unroll
    for (int it = 0; it < NIT; ++it) {
        rx[2 * it]     = rowok ? xrow[it * 8]     : z4;
        rx[2 * it + 1] = rowok ? xrow[it * 8 + 1] : z4;
    }

    #pragma unroll
    for (int it = 0; it < NIT; ++it) {
        float4 c0 = rx[2 * it], c1 = rx[2 * it + 1];
        bt8 af;
        af[0] = (short)f2bf(c0.x); af[1] = (short)f2bf(c0.y);
        af[2] = (short)f2bf(c0.z); af[3] = (short)f2bf(c0.w);
        af[4] = (short)f2bf(c1.x); af[5] = (short)f2bf(c1.y);
        af[6] = (short)f2bf(c1.z); af[7] = (short)f2bf(c1.w);
        #pragma unroll
        for (int g = 0; g < 4; ++g) {
            bt8 bf = *(const bt8*)&wt_l[(16 * g + frow) * LDW + it * 32 + kof];
            acc[g] = __builtin_amdgcn_mfma_f32_16x16x32_bf16(af, bf, acc[g], 0, 0, 0);
        }
    }

    const int orow0 = base + 16 * w + (l >> 4) * 4;
    const int ocol = l & 15;
    #pragma unroll
    for (int g = 0; g < 4; ++g) {
        #pragma unroll
        for (int r4 = 0; r4 < 4; ++r4) {
            int gr = orow0 + r4;
            if (gr < nrows) OUT[(size_t)gr * 64 + 16 * g + ocol] = f2bf(acc[g][r4]);
        }
    }

    // a_dst-only epilogue (a_src computed in-register at gather)
    float ad_c[4];
    #pragma unroll
    for (int g = 0; g < 4; ++g) ad_c[g] = att_d[16 * g + ocol];
    #pragma unroll
    for (int r4 = 0; r4 < 4; ++r4) {
        int gr = orow0 + r4;
        #pragma unroll
        for (int g = 0; g < 4; ++g) {
            float pd = acc[g][r4] * ad_c[g];
            pd += __shfl_xor(pd, 1, 64);
            pd += __shfl_xor(pd, 2, 64);
            pd += __shfl_xor(pd, 4, 64);
            if ((l & 7) == 0 && gr < nrows) {
                int head = 2 * g + ((l >> 3) & 1);
                a_dst[(size_t)gr * 8 + head] = pd;
            }
        }
    }
}

// ---- phase 2: per-bucket histogram + scan + scatter ----
__global__ __launch_bounds__(1024) void phase2_build(
    const uint* __restrict__ pairs, const int* __restrict__ pcur,
    int* __restrict__ rp, int* __restrict__ ssrc, int n, int nbuk_used)
{
    __shared__ int hist[512], cur[512], psc[NBUK];
    const int k = blockIdx.x;
    const int t = threadIdx.x;
    const int beg = k * BCAP;
    const int cnt = pcur[k] - beg;
    const int dbase = k << 9;

    if (t < 512) hist[t] = 0;
    if (t < NBUK) psc[t] = (t < nbuk_used) ? (pcur[t] - t * BCAP) : 0;
    __syncthreads();
    for (int off = 1; off < NBUK; off <<= 1) {
        int add = (t < NBUK && t >= off) ? psc[t - off] : 0;
        __syncthreads();
        if (t < NBUK) psc[t] += add;
        __syncthreads();
    }
    const int bbase = k ? psc[k - 1] : 0;

    for (int i = t; i < cnt; i += 1024)
        atomicAdd(&hist[pairs[beg + i] >> 17], 1);
    __syncthreads();

    int c0 = (t < 512) ? hist[t] : 0;
    for (int off = 1; off < 512; off <<= 1) {
        int add = (t < 512 && t >= off) ? hist[t - off] : 0;
        __syncthreads();
        if (t < 512) hist[t] += add;
        __syncthreads();
    }
    if (t < 512) {
        int node = dbase + t;
        if (node < n) rp[node] = bbase + hist[t];
        cur[t] = hist[t] - c0;
    }
    __syncthreads();

    for (int i = t; i < cnt; i += 1024) {
        uint p = pairs[beg + i];
        int j = p >> 17;
        int pos = bbase + atomicAdd(&cur[j], 1);
        ssrc[pos] = (int)(p & 0x1FFFF);
    }
}

// ---- layer-2 GEMM (bf16 in, LDS-staged pipelined) + FULL att epilogue ----
__global__ __launch_bounds__(256) void gemm2_att(
    const ushort* __restrict__ X, const ushort* __restrict__ WT,
    ushort* __restrict__ OUT, float* __restrict__ a_src, float* __restrict__ a_dst,
    const float* __restrict__ att_s, const float* __restrict__ att_d, int nrows)
{
    constexpr int K = 64, LDW = K + 8, NIT = K / 32;
    __shared__ ushort wt_l[64 * LDW];
    __shared__ ushort a_l[64 * 40];
    const int t = threadIdx.x;
    const int base = blockIdx.x * 64;

    for (int idx = t * 8; idx < 64 * K; idx += 256 * 8) {
        int r = idx / K, c = idx % K;
        *(uint4*)&wt_l[r * LDW + c] = *(const uint4*)&WT[idx];
    }

    const int w = t >> 6, l = t & 63;
    const int frow = l & 15;
    const int kof = (l >> 4) * 8;
    fx4 acc[4] = {};
    uint4 rb;

    auto load_tile = [&](int k0) {
        int r = t >> 2, kq = (t & 3) * 8;
        int gr = base + r;
        rb = make_uint4(0, 0, 0, 0);
        if (gr < nrows) rb = *(const uint4*)(X + (size_t)gr * K + k0 + kq);
    };
    auto store_tile = [&]() {
        int r = t >> 2, kq = (t & 3) * 8;
        *(uint4*)&a_l[r * 40 + kq] = rb;
    };

    load_tile(0);
    store_tile();
    for (int it = 0; it < NIT; ++it) {
        if (it + 1 < NIT) load_tile((it + 1) * 32);
        __syncthreads();
        bt8 af = *(const bt8*)&a_l[(16 * w + frow) * 40 + kof];
        #pragma unroll
        for (int g = 0; g < 4; ++g) {
            bt8 bf = *(const bt8*)&wt_l[(16 * g + frow) * LDW + it * 32 + kof];
            acc[g] = __builtin_amdgcn_mfma_f32_16x16x32_bf16(af, bf, acc[g], 0, 0, 0);
        }
        __syncthreads();
        if (it + 1 < NIT) store_tile();
    }

    const int orow0 = base + 16 * w + (l >> 4) * 4;
    const int ocol = l & 15;
    #pragma unroll
    for (int g = 0; g < 4; ++g) {
        #pragma unroll
        for (int r4 = 0; r4 < 4; ++r4) {
            int gr = orow0 + r4;
            if (gr < nrows) OUT[(size_t)gr * 64 + 16 * g + ocol] = f2bf(acc[g][r4]);
        }
    }

    float as_c[4], ad_c[4];
    #pragma unroll
    for (int g = 0; g < 4; ++g) {
        as_c[g] = att_s[16 * g + ocol];
        ad_c[g] = att_d[16 * g + ocol];
    }
    #pragma unroll
    for (int r4 = 0; r4 < 4; ++r4) {
        int gr = orow0 + r4;
        float ps = 0.f, pd = 0.f;
        #pragma unroll
        for (int g = 0; g < 4; ++g) {
            ps += acc[g][r4] * as_c[g];
            pd += acc[g][r4] * ad_c[g];
        }
        ps += __shfl_xor(ps, 1, 64); pd += __shfl_xor(pd, 1, 64);
        ps += __shfl_xor(ps, 2, 64); pd += __shfl_xor(pd, 2, 64);
        ps += __shfl_xor(ps, 4, 64); pd += __shfl_xor(pd, 4, 64);
        ps += __shfl_xor(ps, 8, 64); pd += __shfl_xor(pd, 8, 64);
        if ((l & 15) == 0 && gr < nrows) {
            a_src[gr] = ps;
            a_dst[gr] = pd;
        }
    }
}

// ---- gather layer 1 (8 heads): in-register scores, single chain ----
__global__ __launch_bounds__(256) void gather_h8(
    const int* __restrict__ rp, const int* __restrict__ ssrc,
    const float* __restrict__ a_dst, const float* __restrict__ att_s,
    const ushort* __restrict__ HB, const float* __restrict__ bias,
    ushort* __restrict__ HACT, int n)
{
    int node = blockIdx.x * 32 + (threadIdx.x >> 3);
    if (node >= n) return;
    int ol = threadIdx.x & 7;
    int end = rp[node];
    int start = node ? rp[node - 1] : 0;
    float adh = a_dst[(size_t)node * 8 + ol];
    float4 w0 = *(const float4*)(att_s + ol * 8);
    float4 w1 = *(const float4*)(att_s + ol * 8 + 4);
    float acc[8] = {};
    float dsum = 0.f;

    int i0 = start;
    for (; i0 + 8 <= end; i0 += 8) {       // full batches: no predication
        int sv = ssrc[i0 + ol];
        #pragma unroll
        for (int j = 0; j < 8; ++j) {
            int sj = __shfl(sv, j, 8);
            EDGE_H8(sj, true);
        }
    }
    if (i0 < end) {                        // tail
        int cnt = end - i0;
        int sv = (ol < cnt) ? ssrc[i0 + ol] : 0;
        #pragma unroll
        for (int j = 0; j < 8; ++j) {
            int sj = __shfl(sv, j, 8);
            EDGE_H8(sj, j < cnt);
        }
    }
    float inv = 1.f / (dsum + 1e-16f);
    float4 b0 = *(const float4*)(bias + ol * 8);
    float4 b1 = *(const float4*)(bias + ol * 8 + 4);
    float v[8];
    v[0] = acc[0] * inv + b0.x; v[1] = acc[1] * inv + b0.y;
    v[2] = acc[2] * inv + b0.z; v[3] = acc[3] * inv + b0.w;
    v[4] = acc[4] * inv + b1.x; v[5] = acc[5] * inv + b1.y;
    v[6] = acc[6] * inv + b1.z; v[7] = acc[7] * inv + b1.w;
    #pragma unroll
    for (int c = 0; c < 8; ++c) v[c] = v[c] > 0.f ? v[c] : expm1f(v[c]);
    uint4 o;
    o.x = (uint)f2bf(v[0]) | ((uint)f2bf(v[1]) << 16);
    o.y = (uint)f2bf(v[2]) | ((uint)f2bf(v[3]) << 16);
    o.z = (uint)f2bf(v[4]) | ((uint)f2bf(v[5]) << 16);
    o.w = (uint)f2bf(v[6]) | ((uint)f2bf(v[7]) << 16);
    *(uint4*)(HACT + (size_t)node * 64 + ol * 8) = o;
}

// ---- gather layer 2 (1 head): r13 form (scalar a_src gather) + lsm ----
__global__ __launch_bounds__(256) void gather_h1_lsm(
    const int* __restrict__ rp, const int* __restrict__ ssrc,
    const float* __restrict__ a_src, const float* __restrict__ a_dst,
    const ushort* __restrict__ HB, const float* __restrict__ bias,
    float* __restrict__ OUT, int n)
{
    int node = blockIdx.x * 32 + (threadIdx.x >> 3);
    if (node >= n) return;
    int ol = threadIdx.x & 7;
    int end = rp[node];
    int start = node ? rp[node - 1] : 0;
    float ad = a_dst[node];
    float acc[8] = {};
    float dsum = 0.f;

    int i0 = start;
    for (; i0 + 16 <= end; i0 += 16) {
        int svA = ssrc[i0 + ol];
        int svB = ssrc[i0 + 8 + ol];
        #pragma unroll
        for (int j = 0; j < 8; ++j) {
            int sjA = __shfl(svA, j, 8);
            float aA = a_src[sjA] + ad;
            aA = aA > 0.f ? aA : LRELU_SLOPE * aA;
            float eA = __expf(aA);
            uint4 hvA = *(const uint4*)(HB + (size_t)sjA * 64 + ol * 8);
            dsum += eA; ACC8(eA, hvA);
            int sjB = __shfl(svB, j, 8);
            float aB = a_src[sjB] + ad;
            aB = aB > 0.f ? aB : LRELU_SLOPE * aB;
            float eB = __expf(aB);
            uint4 hvB = *(const uint4*)(HB + (size_t)sjB * 64 + ol * 8);
            dsum += eB; ACC8(eB, hvB);
        }
    }
    for (; i0 < end; i0 += 8) {
        int cnt = min(8, end - i0);
        int sv = (ol < cnt) ? ssrc[i0 + ol] : 0;
        #pragma unroll
        for (int j = 0; j < 8; ++j) {
            int sj = __shfl(sv, j, 8);
            float a = a_src[sj] + ad;
            a = a > 0.f ? a : LRELU_SLOPE * a;
            float e = __expf(a);
            e = (j < cnt) ? e : 0.f;
            uint4 hv = *(const uint4*)(HB + (size_t)sj * 64 + ol * 8);
            dsum += e; ACC8(e, hv);
        }
    }
    float inv = 1.f / (dsum + 1e-16f);
    float4 b0 = *(const float4*)(bias + ol * 8);
    float4 b1 = *(const float4*)(bias + ol * 8 + 4);
    float v[8];
    v[0] = acc[0] * inv + b0.x; v[1] = acc[1] * inv + b0.y;
    v[2] = acc[2] * inv + b0.z; v[3] = acc[3] * inv + b0.w;
    v[4] = acc[4] * inv + b1.x; v[5] = acc[5] * inv + b1.y;
    v[6] = acc[6] * inv + b1.z; v[7] = acc[7] * inv + b1.w;

    float m = v[0];
    #pragma unroll
    for (int c = 1; c < 8; ++c) m = fmaxf(m, v[c]);
    m = fmaxf(m, __shfl_xor(m, 1, 8));
    m = fmaxf(m, __shfl_xor(m, 2, 8));
    m = fmaxf(m, __shfl_xor(m, 4, 8));
    float s = 0.f;
    #pragma unroll
    for (int c = 0; c < 8; ++c) s += __expf(v[c] - m);
    s += __shfl_xor(s, 1, 8);
    s += __shfl_xor(s, 2, 8);
    s += __shfl_xor(s, 4, 8);
    float lse = m + __logf(s);
    float4 o0 = make_float4(v[0] - lse, v[1] - lse, v[2] - lse, v[3] - lse);
    float4 o1 = make_float4(v[4] - lse, v[5] - lse, v[6] - lse, v[7] - lse);
    *(float4*)(OUT + (size_t)node * 64 + ol * 8) = o0;
    *(float4*)(OUT + (size_t)node * 64 + ol * 8 + 4) = o1;
}

extern "C" void kernel_launch(void* const* d_in, const int* in_sizes, int n_in,
                              void* d_out, int out_size, void* d_ws, size_t ws_size,
                              hipStream_t stream)
{
    const float* x    = (const float*)d_in[0];
    const int*   ei   = (const int*)d_in[1];
    const float* W1   = (const float*)d_in[2];
    const float* as1w = (const float*)d_in[3];
    const float* ad1w = (const float*)d_in[4];
    const float* b1   = (const float*)d_in[5];
    const float* W2   = (const float*)d_in[6];
    const float* as2w = (const float*)d_in[7];
    const float* ad2w = (const float*)d_in[8];
    const float* b2   = (const float*)d_in[9];
    float* out = (float*)d_out;

    const int n  = in_sizes[0] / 256;     // 100000
    const int E_ = in_sizes[1] / 2;       // 1600000
    const int ET = E_ + n;
    const int NBUKU = (n + 511) >> 9;     // 196 used buckets

    // ---- workspace layout: NO aliasing ----
    char* wsb = (char*)d_ws;
    uint*   pairs= (uint*)wsb;                           // [NBUK*BCAP]  9.96 MB
    ushort* HB   = (ushort*)(pairs + (size_t)NBUK*BCAP); // [n*64] bf16  12.8 MB
    ushort* HACT = HB + (size_t)n * 64;                  // [n*64] bf16  12.8 MB
    float*  a_d1 = (float*)(HACT + (size_t)n * 64);      // [n*8]
    float*  a_s2 = a_d1 + (size_t)n * 8;                 // [n]
    float*  a_d2 = a_s2 + n;                             // [n]
    int*    rp   = (int*)(a_d2 + n);                     // [n]
    int*    pcur = rp + n;                               // [NBUK]
    int*    ssrc = pcur + NBUK;                          // [ET]
    ushort* WT1  = (ushort*)(ssrc + ET);                 // [64*256]
    ushort* WT2  = WT1 + 64 * 256;                       // [64*64]

    const int gemm_grid = (n + 63) / 64;
    const int gath_grid = (n + 31) / 32;
    const int part_grid = (ET + CH2 - 1) / CH2;

    // 1. weight prep + cursor init
    prep_init<<<80, 256, 0, stream>>>(W1, W2, WT1, WT2, pcur);
    // 2. edge partition (standalone, r9-proven)
    partition_pairs<<<part_grid, 1024, 0, stream>>>(ei, E_, ET, pcur, pairs);
    // 3. per-bucket CSR finalize (rp + ssrc)
    phase2_build<<<NBUKU, 1024, 0, stream>>>(pairs, pcur, rp, ssrc, n, NBUKU);
    // 4. layer-1 GEMM (full-row register prefetch, barrier-free K-loop) + a_dst
    gemm1_att<<<gemm_grid, 256, 0, stream>>>(x, WT1, HB, a_d1, ad1w, n);
    // 5. layer-1 gather (in-register scores), bf16 out
    gather_h8<<<gath_grid, 256, 0, stream>>>(rp, ssrc, a_d1, as1w, HB, b1, HACT, n);
    // 6. layer-2 GEMM + full att epilogue (a_src2 + a_dst2)
    gemm2_att<<<gemm_grid, 256, 0, stream>>>(HACT, WT2, HB, a_s2, a_d2, as2w, ad2w, n);
    // 7. layer-2 gather (r13 form) + log_softmax
    gather_h1_lsm<<<gath_grid, 256, 0, stream>>>(rp, ssrc, a_s2, a_d2, HB, b2, out, n);
}

// Round 23
// 166.691 us; speedup vs baseline: 1.1241x; 1.1241x over previous
//
#include <hip/hip_runtime.h>
#include <hip/hip_bf16.h>

#define LRELU_SLOPE 0.2f
#define NBUK 256          // dst buckets (512 nodes each)
#define BCAP 9728         // per-bucket capacity (mean 8704, +11 sigma)
#define CH2 6144          // edges per partition block (6/thread, 1024 threads)

typedef unsigned int uint;
typedef unsigned short ushort;
typedef short bt8 __attribute__((ext_vector_type(8)));   // 8 bf16 (4 VGPRs)
typedef float fx4 __attribute__((ext_vector_type(4)));   // MFMA accumulator

__device__ __forceinline__ ushort f2bf(float f) {   // RNE
    uint u = __float_as_uint(f);
    return (ushort)((u + 0x7FFF + ((u >> 16) & 1)) >> 16);
}
__device__ __forceinline__ float bf2f(ushort h) {
    return __uint_as_float(((uint)h) << 16);
}

#define ACC8(e, hv) \
    acc[0] += (e) * bf2f((ushort)((hv).x & 0xffff)); \
    acc[1] += (e) * bf2f((ushort)((hv).x >> 16));    \
    acc[2] += (e) * bf2f((ushort)((hv).y & 0xffff)); \
    acc[3] += (e) * bf2f((ushort)((hv).y >> 16));    \
    acc[4] += (e) * bf2f((ushort)((hv).z & 0xffff)); \
    acc[5] += (e) * bf2f((ushort)((hv).z >> 16));    \
    acc[6] += (e) * bf2f((ushort)((hv).w & 0xffff)); \
    acc[7] += (e) * bf2f((ushort)((hv).w >> 16));

// per-edge step, 8-head gather: score computed in-register from hv (head ol)
#define EDGE_H8(sjv, LIVE) { \
    uint4 hv = *(const uint4*)(HB + (size_t)(sjv) * 64 + ol * 8); \
    float h0 = bf2f((ushort)(hv.x & 0xffff)), h1 = bf2f((ushort)(hv.x >> 16)); \
    float h2 = bf2f((ushort)(hv.y & 0xffff)), h3 = bf2f((ushort)(hv.y >> 16)); \
    float h4 = bf2f((ushort)(hv.z & 0xffff)), h5 = bf2f((ushort)(hv.z >> 16)); \
    float h6 = bf2f((ushort)(hv.w & 0xffff)), h7 = bf2f((ushort)(hv.w >> 16)); \
    float dt = h0*w0.x + h1*w0.y + h2*w0.z + h3*w0.w \
             + h4*w1.x + h5*w1.y + h6*w1.z + h7*w1.w; \
    float a_ = dt + adh; a_ = a_ > 0.f ? a_ : LRELU_SLOPE * a_; \
    float e = __expf(a_); \
    if (!(LIVE)) e = 0.f; \
    dsum += e; \
    acc[0] += e*h0; acc[1] += e*h1; acc[2] += e*h2; acc[3] += e*h3; \
    acc[4] += e*h4; acc[5] += e*h5; acc[6] += e*h6; acc[7] += e*h7; }

// ---- prep: W -> W^T bf16 (both layers) + init pcur ----
__global__ __launch_bounds__(256) void prep_init(
    const float* __restrict__ W1, const float* __restrict__ W2,
    ushort* __restrict__ WT1, ushort* __restrict__ WT2, int* __restrict__ pcur)
{
    int t = threadIdx.x;
    int idx = blockIdx.x * 256 + t;
    if (blockIdx.x == 0) pcur[t] = t * BCAP;
    if (idx < 64 * 256) {
        int c = idx >> 8, k = idx & 255;
        WT1[idx] = f2bf(W1[k * 64 + c]);
    }
    int i2 = idx - 64 * 256;
    if (i2 >= 0 && i2 < 64 * 64) {
        int c = i2 >> 6, k = i2 & 63;
        WT2[i2] = f2bf(W2[k * 64 + c]);
    }
}

// ---- partition body (r9-proven geometry: 1024 threads, 6 edges/thread) ----
__device__ __forceinline__ void partition_body(
    int bid, const int* __restrict__ ei, int E_, int ET,
    int* __restrict__ pcur, uint* __restrict__ pairs,
    int* lcnt, int* lsc, int* lplace, int* gpos)
{
    const int t = threadIdx.x;
    const int base = bid * CH2;
    const int total = min(CH2, ET - base);
    if (total <= 0) return;

    if (t < NBUK) lcnt[t] = 0;
    __syncthreads();

    uint pp[6]; int pk[6];
    #pragma unroll
    for (int i = 0; i < 6; ++i) {
        int idx = t + i * 1024;
        pk[i] = -1;
        if (idx < total) {
            int e = base + idx;
            int s, d;
            if (e < E_) { s = ei[e]; d = ei[E_ + e]; } else { s = d = e - E_; }
            pk[i] = d >> 9;
            pp[i] = (uint)s | ((uint)(d & 511) << 17);
            atomicAdd(&lcnt[pk[i]], 1);
        }
    }
    __syncthreads();

    if (t < NBUK) lsc[t] = lcnt[t];
    __syncthreads();
    for (int off = 1; off < NBUK; off <<= 1) {
        int add = 0;
        if (t < NBUK && t >= off) add = lsc[t - off];
        __syncthreads();
        if (t < NBUK) lsc[t] += add;
        __syncthreads();
    }
    if (t < NBUK) {
        int excl = lsc[t] - lcnt[t];
        lplace[t] = excl;
        int c = lcnt[t];
        gpos[t] = c ? (atomicAdd(&pcur[t], c) - excl) : 0;
    }
    __syncthreads();

    #pragma unroll
    for (int i = 0; i < 6; ++i) {
        if (pk[i] >= 0) {
            int slot = atomicAdd(&lplace[pk[i]], 1);
            pairs[gpos[pk[i]] + slot] = pp[i];
        }
    }
}

// ---- gemm1 body: 4 subtiles/block, LDS-staged A, a_dst-only epilogue ----
__device__ __forceinline__ void gemm1_body4(
    int gbid, const float* __restrict__ X, const ushort* __restrict__ WT,
    ushort* __restrict__ OUT, float* __restrict__ a_dst,
    const float* __restrict__ att_d, int nrows,
    ushort* wt_l, ushort* a_l)
{
    constexpr int K = 256, LDW = K + 8, NIT = K / 32;
    const int t = threadIdx.x;
    const int tt = t & 255;
    const int base = (gbid * 4 + (t >> 8)) * 64;

    for (int idx = t * 8; idx < 64 * K; idx += 1024 * 8) {
        int r = idx / K, c = idx % K;
        *(uint4*)&wt_l[r * LDW + c] = *(const uint4*)&WT[idx];
    }

    const int w = tt >> 6, l = tt & 63;
    const int frow = l & 15;
    const int kof = (l >> 4) * 8;
    fx4 acc[4] = {};
    float4 rv0, rv1;

    auto load_tile = [&](int k0) {
        int kq = (tt & 7) * 4;
        int r0 = (tt >> 3);
        int g0 = base + r0, g1 = base + r0 + 32;
        rv0 = make_float4(0.f, 0.f, 0.f, 0.f);
        rv1 = make_float4(0.f, 0.f, 0.f, 0.f);
        if (g0 < nrows) rv0 = *(const float4*)(X + (size_t)g0 * K + k0 + kq);
        if (g1 < nrows) rv1 = *(const float4*)(X + (size_t)g1 * K + k0 + kq);
    };
    auto store_tile = [&]() {
        int kq = (tt & 7) * 4;
        int r0 = (tt >> 3);
        ushort4 o0, o1;
        o0.x = f2bf(rv0.x); o0.y = f2bf(rv0.y); o0.z = f2bf(rv0.z); o0.w = f2bf(rv0.w);
        o1.x = f2bf(rv1.x); o1.y = f2bf(rv1.y); o1.z = f2bf(rv1.z); o1.w = f2bf(rv1.w);
        *(ushort4*)&a_l[r0 * 40 + kq] = o0;
        *(ushort4*)&a_l[(r0 + 32) * 40 + kq] = o1;
    };

    load_tile(0);
    store_tile();
    for (int it = 0; it < NIT; ++it) {
        if (it + 1 < NIT) load_tile((it + 1) * 32);
        __syncthreads();
        bt8 af = *(const bt8*)&a_l[(16 * w + frow) * 40 + kof];
        #pragma unroll
        for (int g = 0; g < 4; ++g) {
            bt8 bf = *(const bt8*)&wt_l[(16 * g + frow) * LDW + it * 32 + kof];
            acc[g] = __builtin_amdgcn_mfma_f32_16x16x32_bf16(af, bf, acc[g], 0, 0, 0);
        }
        __syncthreads();
        if (it + 1 < NIT) store_tile();
    }

    const int orow0 = base + 16 * w + (l >> 4) * 4;
    const int ocol = l & 15;
    #pragma unroll
    for (int g = 0; g < 4; ++g) {
        #pragma unroll
        for (int r4 = 0; r4 < 4; ++r4) {
            int gr = orow0 + r4;
            if (gr < nrows) OUT[(size_t)gr * 64 + 16 * g + ocol] = f2bf(acc[g][r4]);
        }
    }

    // a_dst-only epilogue (a_src computed in-register at gather)
    float ad_c[4];
    #pragma unroll
    for (int g = 0; g < 4; ++g) ad_c[g] = att_d[16 * g + ocol];
    #pragma unroll
    for (int r4 = 0; r4 < 4; ++r4) {
        int gr = orow0 + r4;
        #pragma unroll
        for (int g = 0; g < 4; ++g) {
            float pd = acc[g][r4] * ad_c[g];
            pd += __shfl_xor(pd, 1, 64);
            pd += __shfl_xor(pd, 2, 64);
            pd += __shfl_xor(pd, 4, 64);
            if ((l & 7) == 0 && gr < nrows) {
                int head = 2 * g + ((l >> 3) & 1);
                a_dst[(size_t)gr * 8 + head] = pd;
            }
        }
    }
}

// ---- fused launch: partition blocks ∥ gemm1 blocks ----
__global__ __launch_bounds__(1024) void part_gemm1(
    const int* __restrict__ ei, int E_, int ET, int part_grid,
    int* __restrict__ pcur, uint* __restrict__ pairs,
    const float* __restrict__ x, const ushort* __restrict__ WT1,
    ushort* __restrict__ HB, float* __restrict__ a_d1,
    const float* __restrict__ att_d, int n)
{
    __shared__ int lcnt[NBUK], lsc[NBUK], lplace[NBUK], gpos[NBUK];   // 4 KB
    __shared__ ushort wt_l[64 * 264];                                 // 33.8 KB
    __shared__ ushort a_l4[4][64 * 40];                               // 20.5 KB
    if ((int)blockIdx.x < part_grid)
        partition_body(blockIdx.x, ei, E_, ET, pcur, pairs, lcnt, lsc, lplace, gpos);
    else
        gemm1_body4(blockIdx.x - part_grid, x, WT1, HB, a_d1,
                    att_d, n, wt_l, a_l4[threadIdx.x >> 8]);
}

// ---- phase 2: per-bucket histogram + scan + scatter ----
__global__ __launch_bounds__(1024) void phase2_build(
    const uint* __restrict__ pairs, const int* __restrict__ pcur,
    int* __restrict__ rp, int* __restrict__ ssrc, int n, int nbuk_used)
{
    __shared__ int hist[512], cur[512], psc[NBUK];
    const int k = blockIdx.x;
    const int t = threadIdx.x;
    const int beg = k * BCAP;
    const int cnt = pcur[k] - beg;
    const int dbase = k << 9;

    if (t < 512) hist[t] = 0;
    if (t < NBUK) psc[t] = (t < nbuk_used) ? (pcur[t] - t * BCAP) : 0;
    __syncthreads();
    for (int off = 1; off < NBUK; off <<= 1) {
        int add = (t < NBUK && t >= off) ? psc[t - off] : 0;
        __syncthreads();
        if (t < NBUK) psc[t] += add;
        __syncthreads();
    }
    const int bbase = k ? psc[k - 1] : 0;

    for (int i = t; i < cnt; i += 1024)
        atomicAdd(&hist[pairs[beg + i] >> 17], 1);
    __syncthreads();

    int c0 = (t < 512) ? hist[t] : 0;
    for (int off = 1; off < 512; off <<= 1) {
        int add = (t < 512 && t >= off) ? hist[t - off] : 0;
        __syncthreads();
        if (t < 512) hist[t] += add;
        __syncthreads();
    }
    if (t < 512) {
        int node = dbase + t;
        if (node < n) rp[node] = bbase + hist[t];
        cur[t] = hist[t] - c0;
    }
    __syncthreads();

    for (int i = t; i < cnt; i += 1024) {
        uint p = pairs[beg + i];
        int j = p >> 17;
        int pos = bbase + atomicAdd(&cur[j], 1);
        ssrc[pos] = (int)(p & 0x1FFFF);
    }
}

// ---- layer-2 GEMM (bf16 in, LDS-staged pipelined) + FULL att epilogue ----
__global__ __launch_bounds__(256) void gemm2_att(
    const ushort* __restrict__ X, const ushort* __restrict__ WT,
    ushort* __restrict__ OUT, float* __restrict__ a_src, float* __restrict__ a_dst,
    const float* __restrict__ att_s, const float* __restrict__ att_d, int nrows)
{
    constexpr int K = 64, LDW = K + 8, NIT = K / 32;
    __shared__ ushort wt_l[64 * LDW];
    __shared__ ushort a_l[64 * 40];
    const int t = threadIdx.x;
    const int base = blockIdx.x * 64;

    for (int idx = t * 8; idx < 64 * K; idx += 256 * 8) {
        int r = idx / K, c = idx % K;
        *(uint4*)&wt_l[r * LDW + c] = *(const uint4*)&WT[idx];
    }

    const int w = t >> 6, l = t & 63;
    const int frow = l & 15;
    const int kof = (l >> 4) * 8;
    fx4 acc[4] = {};
    uint4 rb;

    auto load_tile = [&](int k0) {
        int r = t >> 2, kq = (t & 3) * 8;
        int gr = base + r;
        rb = make_uint4(0, 0, 0, 0);
        if (gr < nrows) rb = *(const uint4*)(X + (size_t)gr * K + k0 + kq);
    };
    auto store_tile = [&]() {
        int r = t >> 2, kq = (t & 3) * 8;
        *(uint4*)&a_l[r * 40 + kq] = rb;
    };

    load_tile(0);
    store_tile();
    for (int it = 0; it < NIT; ++it) {
        if (it + 1 < NIT) load_tile((it + 1) * 32);
        __syncthreads();
        bt8 af = *(const bt8*)&a_l[(16 * w + frow) * 40 + kof];
        #pragma unroll
        for (int g = 0; g < 4; ++g) {
            bt8 bf = *(const bt8*)&wt_l[(16 * g + frow) * LDW + it * 32 + kof];
            acc[g] = __builtin_amdgcn_mfma_f32_16x16x32_bf16(af, bf, acc[g], 0, 0, 0);
        }
        __syncthreads();
        if (it + 1 < NIT) store_tile();
    }

    const int orow0 = base + 16 * w + (l >> 4) * 4;
    const int ocol = l & 15;
    #pragma unroll
    for (int g = 0; g < 4; ++g) {
        #pragma unroll
        for (int r4 = 0; r4 < 4; ++r4) {
            int gr = orow0 + r4;
            if (gr < nrows) OUT[(size_t)gr * 64 + 16 * g + ocol] = f2bf(acc[g][r4]);
        }
    }

    float as_c[4], ad_c[4];
    #pragma unroll
    for (int g = 0; g < 4; ++g) {
        as_c[g] = att_s[16 * g + ocol];
        ad_c[g] = att_d[16 * g + ocol];
    }
    #pragma unroll
    for (int r4 = 0; r4 < 4; ++r4) {
        int gr = orow0 + r4;
        float ps = 0.f, pd = 0.f;
        #pragma unroll
        for (int g = 0; g < 4; ++g) {
            ps += acc[g][r4] * as_c[g];
            pd += acc[g][r4] * ad_c[g];
        }
        ps += __shfl_xor(ps, 1, 64); pd += __shfl_xor(pd, 1, 64);
        ps += __shfl_xor(ps, 2, 64); pd += __shfl_xor(pd, 2, 64);
        ps += __shfl_xor(ps, 4, 64); pd += __shfl_xor(pd, 4, 64);
        ps += __shfl_xor(ps, 8, 64); pd += __shfl_xor(pd, 8, 64);
        if ((l & 15) == 0 && gr < nrows) {
            a_src[gr] = ps;
            a_dst[gr] = pd;
        }
    }
}

// ---- gather layer 1 (8 heads): in-register scores, single chain ----
__global__ __launch_bounds__(256) void gather_h8(
    const int* __restrict__ rp, const int* __restrict__ ssrc,
    const float* __restrict__ a_dst, const float* __restrict__ att_s,
    const ushort* __restrict__ HB, const float* __restrict__ bias,
    ushort* __restrict__ HACT, int n)
{
    int node = blockIdx.x * 32 + (threadIdx.x >> 3);
    if (node >= n) return;
    int ol = threadIdx.x & 7;
    int end = rp[node];
    int start = node ? rp[node - 1] : 0;
    float adh = a_dst[(size_t)node * 8 + ol];
    float4 w0 = *(const float4*)(att_s + ol * 8);
    float4 w1 = *(const float4*)(att_s + ol * 8 + 4);
    float acc[8] = {};
    float dsum = 0.f;

    int i0 = start;
    for (; i0 + 8 <= end; i0 += 8) {       // full batches: no predication
        int sv = ssrc[i0 + ol];
        #pragma unroll
        for (int j = 0; j < 8; ++j) {
            int sj = __shfl(sv, j, 8);
            EDGE_H8(sj, true);
        }
    }
    if (i0 < end) {                        // tail
        int cnt = end - i0;
        int sv = (ol < cnt) ? ssrc[i0 + ol] : 0;
        #pragma unroll
        for (int j = 0; j < 8; ++j) {
            int sj = __shfl(sv, j, 8);
            EDGE_H8(sj, j < cnt);
        }
    }
    float inv = 1.f / (dsum + 1e-16f);
    float4 b0 = *(const float4*)(bias + ol * 8);
    float4 b1 = *(const float4*)(bias + ol * 8 + 4);
    float v[8];
    v[0] = acc[0] * inv + b0.x; v[1] = acc[1] * inv + b0.y;
    v[2] = acc[2] * inv + b0.z; v[3] = acc[3] * inv + b0.w;
    v[4] = acc[4] * inv + b1.x; v[5] = acc[5] * inv + b1.y;
    v[6] = acc[6] * inv + b1.z; v[7] = acc[7] * inv + b1.w;
    #pragma unroll
    for (int c = 0; c < 8; ++c) v[c] = v[c] > 0.f ? v[c] : expm1f(v[c]);
    uint4 o;
    o.x = (uint)f2bf(v[0]) | ((uint)f2bf(v[1]) << 16);
    o.y = (uint)f2bf(v[2]) | ((uint)f2bf(v[3]) << 16);
    o.z = (uint)f2bf(v[4]) | ((uint)f2bf(v[5]) << 16);
    o.w = (uint)f2bf(v[6]) | ((uint)f2bf(v[7]) << 16);
    *(uint4*)(HACT + (size_t)node * 64 + ol * 8) = o;
}

// ---- gather layer 2 (1 head): r13 form (scalar a_src gather) + lsm ----
__global__ __launch_bounds__(256) void gather_h1_lsm(
    const int* __restrict__ rp, const int* __restrict__ ssrc,
    const float* __restrict__ a_src, const float* __restrict__ a_dst,
    const ushort* __restrict__ HB, const float* __restrict__ bias,
    float* __restrict__ OUT, int n)
{
    int node = blockIdx.x * 32 + (threadIdx.x >> 3);
    if (node >= n) return;
    int ol = threadIdx.x & 7;
    int end = rp[node];
    int start = node ? rp[node - 1] : 0;
    float ad = a_dst[node];
    float acc[8] = {};
    float dsum = 0.f;

    int i0 = start;
    for (; i0 + 16 <= end; i0 += 16) {
        int svA = ssrc[i0 + ol];
        int svB = ssrc[i0 + 8 + ol];
        #pragma unroll
        for (int j = 0; j < 8; ++j) {
            int sjA = __shfl(svA, j, 8);
            float aA = a_src[sjA] + ad;
            aA = aA > 0.f ? aA : LRELU_SLOPE * aA;
            float eA = __expf(aA);
            uint4 hvA = *(const uint4*)(HB + (size_t)sjA * 64 + ol * 8);
            dsum += eA; ACC8(eA, hvA);
            int sjB = __shfl(svB, j, 8);
            float aB = a_src[sjB] + ad;
            aB = aB > 0.f ? aB : LRELU_SLOPE * aB;
            float eB = __expf(aB);
            uint4 hvB = *(const uint4*)(HB + (size_t)sjB * 64 + ol * 8);
            dsum += eB; ACC8(eB, hvB);
        }
    }
    for (; i0 < end; i0 += 8) {
        int cnt = min(8, end - i0);
        int sv = (ol < cnt) ? ssrc[i0 + ol] : 0;
        #pragma unroll
        for (int j = 0; j < 8; ++j) {
            int sj = __shfl(sv, j, 8);
            float a = a_src[sj] + ad;
            a = a > 0.f ? a : LRELU_SLOPE * a;
            float e = __expf(a);
            e = (j < cnt) ? e : 0.f;
            uint4 hv = *(const uint4*)(HB + (size_t)sj * 64 + ol * 8);
            dsum += e; ACC8(e, hv);
        }
    }
    float inv = 1.f / (dsum + 1e-16f);
    float4 b0 = *(const float4*)(bias + ol * 8);
    float4 b1 = *(const float4*)(bias + ol * 8 + 4);
    float v[8];
    v[0] = acc[0] * inv + b0.x; v[1] = acc[1] * inv + b0.y;
    v[2] = acc[2] * inv + b0.z; v[3] = acc[3] * inv + b0.w;
    v[4] = acc[4] * inv + b1.x; v[5] = acc[5] * inv + b1.y;
    v[6] = acc[6] * inv + b1.z; v[7] = acc[7] * inv + b1.w;

    float m = v[0];
    #pragma unroll
    for (int c = 1; c < 8; ++c) m = fmaxf(m, v[c]);
    m = fmaxf(m, __shfl_xor(m, 1, 8));
    m = fmaxf(m, __shfl_xor(m, 2, 8));
    m = fmaxf(m, __shfl_xor(m, 4, 8));
    float s = 0.f;
    #pragma unroll
    for (int c = 0; c < 8; ++c) s += __expf(v[c] - m);
    s += __shfl_xor(s, 1, 8);
    s += __shfl_xor(s, 2, 8);
    s += __shfl_xor(s, 4, 8);
    float lse = m + __logf(s);
    float4 o0 = make_float4(v[0] - lse, v[1] - lse, v[2] - lse, v[3] - lse);
    float4 o1 = make_float4(v[4] - lse, v[5] - lse, v[6] - lse, v[7] - lse);
    *(float4*)(OUT + (size_t)node * 64 + ol * 8) = o0;
    *(float4*)(OUT + (size_t)node * 64 + ol * 8 + 4) = o1;
}

extern "C" void kernel_launch(void* const* d_in, const int* in_sizes, int n_in,
                              void* d_out, int out_size, void* d_ws, size_t ws_size,
                              hipStream_t stream)
{
    const float* x    = (const float*)d_in[0];
    const int*   ei   = (const int*)d_in[1];
    const float* W1   = (const float*)d_in[2];
    const float* as1w = (const float*)d_in[3];
    const float* ad1w = (const float*)d_in[4];
    const float* b1   = (const float*)d_in[5];
    const float* W2   = (const float*)d_in[6];
    const float* as2w = (const float*)d_in[7];
    const float* ad2w = (const float*)d_in[8];
    const float* b2   = (const float*)d_in[9];
    float* out = (float*)d_out;

    const int n  = in_sizes[0] / 256;     // 100000
    const int E_ = in_sizes[1] / 2;       // 1600000
    const int ET = E_ + n;
    const int NBUKU = (n + 511) >> 9;     // 196 used buckets

    // ---- workspace layout: NO aliasing ----
    char* wsb = (char*)d_ws;
    uint*   pairs= (uint*)wsb;                           // [NBUK*BCAP]  9.96 MB
    ushort* HB   = (ushort*)(pairs + (size_t)NBUK*BCAP); // [n*64] bf16  12.8 MB
    ushort* HACT = HB + (size_t)n * 64;                  // [n*64] bf16  12.8 MB
    float*  a_d1 = (float*)(HACT + (size_t)n * 64);      // [n*8]
    float*  a_s2 = a_d1 + (size_t)n * 8;                 // [n]
    float*  a_d2 = a_s2 + n;                             // [n]
    int*    rp   = (int*)(a_d2 + n);                     // [n]
    int*    pcur = rp + n;                               // [NBUK]
    int*    ssrc = pcur + NBUK;                          // [ET]
    ushort* WT1  = (ushort*)(ssrc + ET);                 // [64*256]
    ushort* WT2  = WT1 + 64 * 256;                       // [64*64]

    const int gemm_grid  = (n + 63) / 64;
    const int gemm_grid4 = (n + 255) / 256;
    const int gath_grid  = (n + 31) / 32;
    const int part_grid  = (ET + CH2 - 1) / CH2;

    // 1. weight prep + cursor init
    prep_init<<<80, 256, 0, stream>>>(W1, W2, WT1, WT2, pcur);
    // 2. edge partition ∥ layer-1 GEMM (LDS-staged) + a_dst epilogue
    part_gemm1<<<part_grid + gemm_grid4, 1024, 0, stream>>>(
        ei, E_, ET, part_grid, pcur, pairs, x, WT1, HB, a_d1, ad1w, n);
    // 3. per-bucket CSR finalize (rp + ssrc)
    phase2_build<<<NBUKU, 1024, 0, stream>>>(pairs, pcur, rp, ssrc, n, NBUKU);
    // 4. layer-1 gather (in-register scores), bf16 out
    gather_h8<<<gath_grid, 256, 0, stream>>>(rp, ssrc, a_d1, as1w, HB, b1, HACT, n);
    // 5. layer-2 GEMM + full att epilogue (a_src2 + a_dst2)
    gemm2_att<<<gemm_grid, 256, 0, stream>>>(HACT, WT2, HB, a_s2, a_d2, as2w, ad2w, n);
    // 6. layer-2 gather (r13 form) + log_softmax
    gather_h1_lsm<<<gath_grid, 256, 0, stream>>>(rp, ssrc, a_s2, a_d2, HB, b2, out, n);
}